// Round 10
// baseline (52.669 us; speedup 1.0000x reference)
//
#include <hip/hip_runtime.h>
#include <hip/hip_cooperative_groups.h>

namespace cg = cooperative_groups;

#define L 3072
#define NT 512
#define CUT2 5.76f   // 2.4^2
#define GRID 256
#define BLOCK 1024
#define MAXRPB 12    // ceil(3072/256)

typedef unsigned int u32;
typedef unsigned long long u64;

// ---------------------------------------------------------------------------
// Fully fused single dispatch (cooperative). 256 blocks x 1024 threads =
// 1 block/CU, all co-resident. Each block redundantly compacts col/row
// lists into LDS; columns-outer/rows-inner compute (R9 structure); partials
// via relaxed agent atomics; grid.sync(); block 0 reduces and writes out.
// ---------------------------------------------------------------------------
__global__ __launch_bounds__(BLOCK) void plbl_fused(
    const int* __restrict__ is_ligand,
    const int* __restrict__ token_bonds,
    const int* __restrict__ tokmap,
    const int* __restrict__ crd,
    const float* __restrict__ X,
    const float* __restrict__ Xgt,
    double* __restrict__ part_sum,
    u32* __restrict__ part_cnt,
    float* __restrict__ out)
{
    const int t = threadIdx.x;
    const int lane = t & 63;
    const int wv = t >> 6;

    __shared__ u64 s_lig[8];           // is_ligand bitmask (512 tokens)
    __shared__ u32 s_wtot[2][16];
    __shared__ u32 s_colmeta[3072];
    __shared__ u32 s_rowlist[3072];
    __shared__ u64 s_bond[MAXRPB][8];
    __shared__ __align__(16) float s_rowc[MAXRPB][12];
    __shared__ u32 s_rbits[MAXRPB];
    __shared__ double s_rsum[16];
    __shared__ u32 s_rcnt[16];

    // ---- ligand bitmask ---------------------------------------------------
    if (t < NT) {
        const bool v = is_ligand[t] != 0;
        const u64 bal = __ballot(v);
        if (lane == 0) s_lig[wv] = bal;
    }
    __syncthreads();

    // ---------------- Phase A: in-LDS compaction --------------------------
    u32 cc = 0, rc = 0;
    u32 meta[3];
    bool cok[3], rok[3];
    #pragma unroll
    for (int k = 0; k < 3; k++) {
        const int a = t * 3 + k;
        const u32 tok = (u32)tokmap[a];
        const bool lig = (s_lig[tok >> 6] >> (tok & 63)) & 1ULL;
        const u32 m0 = crd[a] != 0;
        const u32 m1 = crd[L + a] != 0;
        const bool any = (m0 | m1) != 0u;
        meta[k] = (u32)a | (tok << 12) | (m0 << 21) | (m1 << 22);
        cok[k] = (!lig) && any;
        rok[k] = lig && any;
        cc += cok[k] ? 1u : 0u;
        rc += rok[k] ? 1u : 0u;
    }

    u32 ci = cc, ri = rc;
    #pragma unroll
    for (int o = 1; o < 64; o <<= 1) {
        u32 cv = __shfl_up(ci, o, 64);
        u32 rv = __shfl_up(ri, o, 64);
        if (lane >= o) { ci += cv; ri += rv; }
    }
    if (lane == 63) { s_wtot[0][wv] = ci; s_wtot[1][wv] = ri; }
    __syncthreads();

    // Redundant per-wave scan of the 16 wave totals (no serial wave-0 phase,
    // no extra barrier).
    u32 cex, rex;
    int ncol, nrow;
    {
        u32 cs = (lane < 16) ? s_wtot[0][lane] : 0u;
        u32 rs = (lane < 16) ? s_wtot[1][lane] : 0u;
        #pragma unroll
        for (int o = 1; o < 16; o <<= 1) {
            u32 cv = __shfl_up(cs, o, 64);
            u32 rv = __shfl_up(rs, o, 64);
            if (lane >= o && lane < 16) { cs += cv; rs += rv; }
        }
        cex = (wv == 0) ? 0u : __shfl(cs, wv - 1, 64);
        rex = (wv == 0) ? 0u : __shfl(rs, wv - 1, 64);
        ncol = (int)__shfl(cs, 15, 64);
        nrow = (int)__shfl(rs, 15, 64);
    }

    u32 coff = cex + (ci - cc);
    u32 roff = rex + (ri - rc);
    #pragma unroll
    for (int k = 0; k < 3; k++) {
        if (cok[k]) s_colmeta[coff++] = meta[k];
        if (rok[k]) s_rowlist[roff++] = meta[k];
    }
    __syncthreads();

    // ---------------- Phase B staging: bond masks + row coords ------------
    const int rpb = (nrow + GRID - 1) / GRID;
    const int r0 = blockIdx.x * rpb;
    const int r1 = (r0 + rpb < nrow) ? (r0 + rpb) : nrow;
    const int nr = (r1 > r0) ? (r1 - r0) : 0;

    // Bond rows: waves 0-7 take even rows, waves 8-15 odd rows (2x faster).
    {
        const int half = wv >> 3;
        const int w8 = wv & 7;
        for (int r = half; r < nr; r += 2) {
            const u32 rm = s_rowlist[r0 + r];
            const u32 ta1 = (rm >> 12) & 0x1FF;
            const int tokidx = (w8 << 6) | lane;
            const bool bv = token_bonds[ta1 * NT + tokidx] != 0;
            const u64 bal = __ballot(bv);
            if (lane == 0) s_bond[r][w8] = bal;
        }
    }
    if (t >= 512 + 64) { /* other waves fall through */ }
    if (t < nr * 12) {
        const int r = t / 12, c = t % 12;
        const u32 rm = s_rowlist[r0 + r];
        const int a1 = (int)(rm & 0xFFF);
        const int batch = (c % 6) / 3;
        const int axis  = c % 3;
        const float* src = (c < 6) ? X : Xgt;
        s_rowc[r][c] = src[(batch * L + a1) * 3 + axis];
    }
    if (t < nr) s_rbits[t] = (s_rowlist[r0 + t] >> 21) & 3u;
    __syncthreads();

    // ---------------- Phase B: columns outer (regs), rows inner -----------
    double acc = 0.0;
    u32 cnt = 0;

    for (int j = t; j < ncol; j += BLOCK) {
        const u32 cm = s_colmeta[j];
        const int a2 = (int)(cm & 0xFFF);
        const u32 tok = (cm >> 12) & 0x1FF;
        const u32 cbits = (cm >> 21) & 3u;
        const u32 bhi = tok >> 6;
        const u64 bsel = 1ULL << (tok & 63);

        const int b0 = 3 * a2;
        const int b1 = 3 * L + 3 * a2;
        const float vx0 = X[b0 + 0], vy0 = X[b0 + 1], vz0 = X[b0 + 2];
        const float vx1 = X[b1 + 0], vy1 = X[b1 + 1], vz1 = X[b1 + 2];
        const float wx0 = Xgt[b0 + 0], wy0 = Xgt[b0 + 1], wz0 = Xgt[b0 + 2];
        const float wx1 = Xgt[b1 + 0], wy1 = Xgt[b1 + 1], wz1 = Xgt[b1 + 2];

        for (int r = 0; r < nr; r++) {
            const bool bond = (s_bond[r][bhi] & bsel) != 0ULL;
            const u32 mb = s_rbits[r] & cbits;

            const float p0x = s_rowc[r][0], p0y = s_rowc[r][1], p0z = s_rowc[r][2];
            const float p1x = s_rowc[r][3], p1y = s_rowc[r][4], p1z = s_rowc[r][5];
            const float g0x = s_rowc[r][6], g0y = s_rowc[r][7], g0z = s_rowc[r][8];
            const float g1x = s_rowc[r][9], g1y = s_rowc[r][10], g1z = s_rowc[r][11];

            // batch 0
            const float dgx0 = g0x - wx0, dgy0 = g0y - wy0, dgz0 = g0z - wz0;
            const float gt2_0 = dgx0 * dgx0 + dgy0 * dgy0 + dgz0 * dgz0;
            const float dpx0 = p0x - vx0, dpy0 = p0y - vy0, dpz0 = p0z - vz0;
            const float pr2_0 = dpx0 * dpx0 + dpy0 * dpy0 + dpz0 * dpz0;
            const float d0 = sqrtf(pr2_0) - sqrtf(gt2_0);
            const bool k0 = bond && (mb & 1u) && (gt2_0 < CUT2);
            // batch 1
            const float dgx1 = g1x - wx1, dgy1 = g1y - wy1, dgz1 = g1z - wz1;
            const float gt2_1 = dgx1 * dgx1 + dgy1 * dgy1 + dgz1 * dgz1;
            const float dpx1 = p1x - vx1, dpy1 = p1y - vy1, dpz1 = p1z - vz1;
            const float pr2_1 = dpx1 * dpx1 + dpy1 * dpy1 + dpz1 * dpz1;
            const float d1 = sqrtf(pr2_1) - sqrtf(gt2_1);
            const bool k1 = bond && (mb & 2u) && (gt2_1 < CUT2);

            const float e = (k0 ? d0 * d0 : 0.0f) + (k1 ? d1 * d1 : 0.0f);
            acc += (double)e;
            cnt += (k0 ? 1u : 0u) + (k1 ? 1u : 0u);
        }
    }

    // ---------------- Block reduction (16 waves) --------------------------
    #pragma unroll
    for (int o = 32; o > 0; o >>= 1) {
        acc += __shfl_down(acc, o, 64);
        cnt += __shfl_down(cnt, o, 64);
    }
    if (lane == 0) { s_rsum[wv] = acc; s_rcnt[wv] = cnt; }
    __syncthreads();
    if (t == 0) {
        double a = 0.0;
        u32 c = 0;
        #pragma unroll
        for (int i = 0; i < 16; i++) { a += s_rsum[i]; c += s_rcnt[i]; }
        __hip_atomic_store(&part_sum[blockIdx.x], a, __ATOMIC_RELAXED,
                           __HIP_MEMORY_SCOPE_AGENT);
        __hip_atomic_store(&part_cnt[blockIdx.x], c, __ATOMIC_RELAXED,
                           __HIP_MEMORY_SCOPE_AGENT);
        asm volatile("s_waitcnt vmcnt(0)" ::: "memory");
    }

    cg::this_grid().sync();

    // ---------------- Block 0: final deterministic reduce -----------------
    if (blockIdx.x == 0) {
        double a = 0.0;
        u32 c = 0;
        if (t < GRID) {
            a = __hip_atomic_load(&part_sum[t], __ATOMIC_RELAXED,
                                  __HIP_MEMORY_SCOPE_AGENT);
            c = __hip_atomic_load(&part_cnt[t], __ATOMIC_RELAXED,
                                  __HIP_MEMORY_SCOPE_AGENT);
        }
        #pragma unroll
        for (int o = 32; o > 0; o >>= 1) {
            a += __shfl_down(a, o, 64);
            c += __shfl_down(c, o, 64);
        }
        __syncthreads();   // s_rsum/s_rcnt reuse
        if (lane == 0) { s_rsum[wv] = a; s_rcnt[wv] = c; }
        __syncthreads();
        if (t == 0) {
            double sum = 0.0;
            u32 cc2 = 0;
            #pragma unroll
            for (int i = 0; i < 16; i++) { sum += s_rsum[i]; cc2 += s_rcnt[i]; }
            const u32 n = cc2 ? cc2 : 1u;
            const float loss = (float)(sum / (double)n);
            out[0] = loss;
            out[1] = loss;
        }
    }
}

extern "C" void kernel_launch(void* const* d_in, const int* in_sizes, int n_in,
                              void* d_out, int out_size, void* d_ws, size_t ws_size,
                              hipStream_t stream) {
    const int*   is_ligand   = (const int*)d_in[0];
    const int*   token_bonds = (const int*)d_in[1];
    const int*   tokmap      = (const int*)d_in[2];
    const int*   crd_mask    = (const int*)d_in[3];
    const float* X           = (const float*)d_in[4];
    const float* Xgt         = (const float*)d_in[5];
    float* out = (float*)d_out;

    char* w = (char*)d_ws;
    double* part_sum = (double*)(w + 0);
    u32*    part_cnt = (u32*)(w + 8 * GRID);

    void* args[] = {
        (void*)&is_ligand, (void*)&token_bonds, (void*)&tokmap,
        (void*)&crd_mask, (void*)&X, (void*)&Xgt,
        (void*)&part_sum, (void*)&part_cnt, (void*)&out
    };
    hipLaunchCooperativeKernel((const void*)plbl_fused,
                               dim3(GRID), dim3(BLOCK), args, 0, stream);
}

// Round 11
// 17.183 us; speedup vs baseline: 3.0652x; 3.0652x over previous
//
#include <hip/hip_runtime.h>

#define L 3072
#define NT 512
#define CUT2 5.76f   // 2.4^2
#define GRID 256
#define BLOCK 1024
#define MAXRPB 12    // ceil(3072/256)
#define MAGIC 0x5AFEC0DEu

typedef unsigned int u32;
typedef unsigned long long u64;

// ---------------------------------------------------------------------------
// Single dispatch, no grid.sync, no ticket. 256 blocks x 1024 threads
// (1 block/CU, all co-resident). Per-block: redundant in-LDS compaction,
// columns-outer/rows-inner compute, partial store + per-block MAGIC flag
// (distinct addresses -> no contention). Block 0 polls the 256 flags with
// relaxed loads and does the final deterministic reduce.
// ---------------------------------------------------------------------------
__global__ __launch_bounds__(BLOCK) void plbl_fused(
    const int* __restrict__ is_ligand,
    const int* __restrict__ token_bonds,
    const int* __restrict__ tokmap,
    const int* __restrict__ crd,
    const float* __restrict__ X,
    const float* __restrict__ Xgt,
    double* __restrict__ part_sum,
    u32* __restrict__ part_cnt,
    u32* __restrict__ part_flag,
    float* __restrict__ out)
{
    const int t = threadIdx.x;
    const int lane = t & 63;
    const int wv = t >> 6;

    __shared__ u64 s_lig[8];           // is_ligand bitmask (512 tokens)
    __shared__ u32 s_wtot[2][16];
    __shared__ u32 s_colmeta[3072];
    __shared__ u32 s_rowlist[3072];
    __shared__ u64 s_bond[MAXRPB][8];
    __shared__ __align__(16) float s_rowc[MAXRPB][12];
    __shared__ u32 s_rbits[MAXRPB];
    __shared__ double s_rsum[16];
    __shared__ u32 s_rcnt[16];

    // ---- ligand bitmask ---------------------------------------------------
    if (t < NT) {
        const bool v = is_ligand[t] != 0;
        const u64 bal = __ballot(v);
        if (lane == 0) s_lig[wv] = bal;
    }
    __syncthreads();

    // ---------------- Phase A: in-LDS compaction --------------------------
    u32 cc = 0, rc = 0;
    u32 meta[3];
    bool cok[3], rok[3];
    #pragma unroll
    for (int k = 0; k < 3; k++) {
        const int a = t * 3 + k;
        const u32 tok = (u32)tokmap[a];
        const bool lig = (s_lig[tok >> 6] >> (tok & 63)) & 1ULL;
        const u32 m0 = crd[a] != 0;
        const u32 m1 = crd[L + a] != 0;
        const bool any = (m0 | m1) != 0u;
        meta[k] = (u32)a | (tok << 12) | (m0 << 21) | (m1 << 22);
        cok[k] = (!lig) && any;
        rok[k] = lig && any;
        cc += cok[k] ? 1u : 0u;
        rc += rok[k] ? 1u : 0u;
    }

    u32 ci = cc, ri = rc;
    #pragma unroll
    for (int o = 1; o < 64; o <<= 1) {
        u32 cv = __shfl_up(ci, o, 64);
        u32 rv = __shfl_up(ri, o, 64);
        if (lane >= o) { ci += cv; ri += rv; }
    }
    if (lane == 63) { s_wtot[0][wv] = ci; s_wtot[1][wv] = ri; }
    __syncthreads();

    // Redundant per-wave scan of the 16 wave totals (validated in R10).
    u32 cex, rex;
    int ncol, nrow;
    {
        u32 cs = (lane < 16) ? s_wtot[0][lane] : 0u;
        u32 rs = (lane < 16) ? s_wtot[1][lane] : 0u;
        #pragma unroll
        for (int o = 1; o < 16; o <<= 1) {
            u32 cv = __shfl_up(cs, o, 64);
            u32 rv = __shfl_up(rs, o, 64);
            if (lane >= o && lane < 16) { cs += cv; rs += rv; }
        }
        cex = (wv == 0) ? 0u : __shfl(cs, wv - 1, 64);
        rex = (wv == 0) ? 0u : __shfl(rs, wv - 1, 64);
        ncol = (int)__shfl(cs, 15, 64);
        nrow = (int)__shfl(rs, 15, 64);
    }

    u32 coff = cex + (ci - cc);
    u32 roff = rex + (ri - rc);
    #pragma unroll
    for (int k = 0; k < 3; k++) {
        if (cok[k]) s_colmeta[coff++] = meta[k];
        if (rok[k]) s_rowlist[roff++] = meta[k];
    }
    __syncthreads();

    // ---------------- Phase B staging: bond masks + row coords ------------
    const int rpb = (nrow + GRID - 1) / GRID;
    const int r0 = blockIdx.x * rpb;
    const int r1 = (r0 + rpb < nrow) ? (r0 + rpb) : nrow;
    const int nr = (r1 > r0) ? (r1 - r0) : 0;

    // Bond rows: waves 0-7 take even rows, waves 8-15 odd rows.
    {
        const int half = wv >> 3;
        const int w8 = wv & 7;
        for (int r = half; r < nr; r += 2) {
            const u32 rm = s_rowlist[r0 + r];
            const u32 ta1 = (rm >> 12) & 0x1FF;
            const int tokidx = (w8 << 6) | lane;
            const bool bv = token_bonds[ta1 * NT + tokidx] != 0;
            const u64 bal = __ballot(bv);
            if (lane == 0) s_bond[r][w8] = bal;
        }
    }
    if (t < nr * 12) {
        const int r = t / 12, c = t % 12;
        const u32 rm = s_rowlist[r0 + r];
        const int a1 = (int)(rm & 0xFFF);
        const int batch = (c % 6) / 3;
        const int axis  = c % 3;
        const float* src = (c < 6) ? X : Xgt;
        s_rowc[r][c] = src[(batch * L + a1) * 3 + axis];
    }
    if (t < nr) s_rbits[t] = (s_rowlist[r0 + t] >> 21) & 3u;
    __syncthreads();

    // ---------------- Phase B: columns outer (regs), rows inner -----------
    double acc = 0.0;
    u32 cnt = 0;

    for (int j = t; j < ncol; j += BLOCK) {
        const u32 cm = s_colmeta[j];
        const int a2 = (int)(cm & 0xFFF);
        const u32 tok = (cm >> 12) & 0x1FF;
        const u32 cbits = (cm >> 21) & 3u;
        const u32 bhi = tok >> 6;
        const u64 bsel = 1ULL << (tok & 63);

        const int b0 = 3 * a2;
        const int b1 = 3 * L + 3 * a2;
        const float vx0 = X[b0 + 0], vy0 = X[b0 + 1], vz0 = X[b0 + 2];
        const float vx1 = X[b1 + 0], vy1 = X[b1 + 1], vz1 = X[b1 + 2];
        const float wx0 = Xgt[b0 + 0], wy0 = Xgt[b0 + 1], wz0 = Xgt[b0 + 2];
        const float wx1 = Xgt[b1 + 0], wy1 = Xgt[b1 + 1], wz1 = Xgt[b1 + 2];

        for (int r = 0; r < nr; r++) {
            const bool bond = (s_bond[r][bhi] & bsel) != 0ULL;
            const u32 mb = s_rbits[r] & cbits;

            const float p0x = s_rowc[r][0], p0y = s_rowc[r][1], p0z = s_rowc[r][2];
            const float p1x = s_rowc[r][3], p1y = s_rowc[r][4], p1z = s_rowc[r][5];
            const float g0x = s_rowc[r][6], g0y = s_rowc[r][7], g0z = s_rowc[r][8];
            const float g1x = s_rowc[r][9], g1y = s_rowc[r][10], g1z = s_rowc[r][11];

            // batch 0
            const float dgx0 = g0x - wx0, dgy0 = g0y - wy0, dgz0 = g0z - wz0;
            const float gt2_0 = dgx0 * dgx0 + dgy0 * dgy0 + dgz0 * dgz0;
            const float dpx0 = p0x - vx0, dpy0 = p0y - vy0, dpz0 = p0z - vz0;
            const float pr2_0 = dpx0 * dpx0 + dpy0 * dpy0 + dpz0 * dpz0;
            const float d0 = sqrtf(pr2_0) - sqrtf(gt2_0);
            const bool k0 = bond && (mb & 1u) && (gt2_0 < CUT2);
            // batch 1
            const float dgx1 = g1x - wx1, dgy1 = g1y - wy1, dgz1 = g1z - wz1;
            const float gt2_1 = dgx1 * dgx1 + dgy1 * dgy1 + dgz1 * dgz1;
            const float dpx1 = p1x - vx1, dpy1 = p1y - vy1, dpz1 = p1z - vz1;
            const float pr2_1 = dpx1 * dpx1 + dpy1 * dpy1 + dpz1 * dpz1;
            const float d1 = sqrtf(pr2_1) - sqrtf(gt2_1);
            const bool k1 = bond && (mb & 2u) && (gt2_1 < CUT2);

            const float e = (k0 ? d0 * d0 : 0.0f) + (k1 ? d1 * d1 : 0.0f);
            acc += (double)e;
            cnt += (k0 ? 1u : 0u) + (k1 ? 1u : 0u);
        }
    }

    // ---------------- Block reduction (16 waves) --------------------------
    #pragma unroll
    for (int o = 32; o > 0; o >>= 1) {
        acc += __shfl_down(acc, o, 64);
        cnt += __shfl_down(cnt, o, 64);
    }
    if (lane == 0) { s_rsum[wv] = acc; s_rcnt[wv] = cnt; }
    __syncthreads();
    if (t == 0) {
        double a = 0.0;
        u32 c = 0;
        #pragma unroll
        for (int i = 0; i < 16; i++) { a += s_rsum[i]; c += s_rcnt[i]; }
        // Partial to coherent point, drain, then flag (distinct address).
        __hip_atomic_store(&part_sum[blockIdx.x], a, __ATOMIC_RELAXED,
                           __HIP_MEMORY_SCOPE_AGENT);
        __hip_atomic_store(&part_cnt[blockIdx.x], c, __ATOMIC_RELAXED,
                           __HIP_MEMORY_SCOPE_AGENT);
        asm volatile("s_waitcnt vmcnt(0)" ::: "memory");
        __hip_atomic_store(&part_flag[blockIdx.x], MAGIC, __ATOMIC_RELAXED,
                           __HIP_MEMORY_SCOPE_AGENT);
    }

    // ---------------- Block 0: poll flags, final reduce -------------------
    if (blockIdx.x == 0) {
        double a = 0.0;
        u32 c = 0;
        if (t < GRID) {
            while (__hip_atomic_load(&part_flag[t], __ATOMIC_RELAXED,
                                     __HIP_MEMORY_SCOPE_AGENT) != MAGIC) {
                __builtin_amdgcn_s_sleep(2);
            }
            a = __hip_atomic_load(&part_sum[t], __ATOMIC_RELAXED,
                                  __HIP_MEMORY_SCOPE_AGENT);
            c = __hip_atomic_load(&part_cnt[t], __ATOMIC_RELAXED,
                                  __HIP_MEMORY_SCOPE_AGENT);
        }
        #pragma unroll
        for (int o = 32; o > 0; o >>= 1) {
            a += __shfl_down(a, o, 64);
            c += __shfl_down(c, o, 64);
        }
        __syncthreads();   // prior s_rsum use complete before reuse
        if (lane == 0) { s_rsum[wv] = a; s_rcnt[wv] = c; }
        __syncthreads();
        if (t == 0) {
            double sum = 0.0;
            u32 cc2 = 0;
            #pragma unroll
            for (int i = 0; i < 16; i++) { sum += s_rsum[i]; cc2 += s_rcnt[i]; }
            const u32 n = cc2 ? cc2 : 1u;
            const float loss = (float)(sum / (double)n);
            out[0] = loss;
            out[1] = loss;
        }
    }
}

extern "C" void kernel_launch(void* const* d_in, const int* in_sizes, int n_in,
                              void* d_out, int out_size, void* d_ws, size_t ws_size,
                              hipStream_t stream) {
    const int*   is_ligand   = (const int*)d_in[0];
    const int*   token_bonds = (const int*)d_in[1];
    const int*   tokmap      = (const int*)d_in[2];
    const int*   crd_mask    = (const int*)d_in[3];
    const float* X           = (const float*)d_in[4];
    const float* Xgt         = (const float*)d_in[5];
    float* out = (float*)d_out;

    char* w = (char*)d_ws;
    double* part_sum  = (double*)(w + 0);
    u32*    part_cnt  = (u32*)(w + 2048);
    u32*    part_flag = (u32*)(w + 3072);

    plbl_fused<<<GRID, BLOCK, 0, stream>>>(is_ligand, token_bonds, tokmap,
                                           crd_mask, X, Xgt,
                                           part_sum, part_cnt, part_flag, out);
}

// Round 12
// 16.788 us; speedup vs baseline: 3.1372x; 1.0235x over previous
//
#include <hip/hip_runtime.h>

#define L 3072
#define NT 512
#define CUT2 5.76f   // 2.4^2
#define GRID 256
#define BLOCK 1024
#define MAXRPB 12    // ceil(3072/256)

typedef unsigned int u32;
typedef unsigned long long u64;

// ---------------------------------------------------------------------------
// Main: 256 blocks x 1024 threads (1 block/CU). Redundant in-LDS compaction
// per block with COALESCED atom assignment (thread t owns atoms t, t+1024,
// t+2048 -> all Phase A loads unit-stride); per-wave redundant scan (no
// serial wave-0 phase); 16-wave bond staging; columns-outer/rows-inner
// compute. Plain partial stores; tiny fin dispatch does the final reduce.
// ---------------------------------------------------------------------------
__global__ __launch_bounds__(BLOCK) void plbl_main(
    const int* __restrict__ is_ligand,
    const int* __restrict__ token_bonds,
    const int* __restrict__ tokmap,
    const int* __restrict__ crd,
    const float* __restrict__ X,
    const float* __restrict__ Xgt,
    double* __restrict__ part_sum,
    u32* __restrict__ part_cnt)
{
    const int t = threadIdx.x;
    const int lane = t & 63;
    const int wv = t >> 6;

    __shared__ u64 s_lig[8];           // is_ligand bitmask (512 tokens)
    __shared__ u32 s_wtot[2][16];
    __shared__ u32 s_colmeta[3072];
    __shared__ u32 s_rowlist[3072];
    __shared__ u64 s_bond[MAXRPB][8];
    __shared__ __align__(16) float s_rowc[MAXRPB][12];
    __shared__ u32 s_rbits[MAXRPB];
    __shared__ double s_rsum[16];
    __shared__ u32 s_rcnt[16];

    // ---- ligand bitmask ---------------------------------------------------
    if (t < NT) {
        const bool v = is_ligand[t] != 0;
        const u64 bal = __ballot(v);
        if (lane == 0) s_lig[wv] = bal;
    }
    __syncthreads();

    // ---------------- Phase A: in-LDS compaction (coalesced) --------------
    u32 cc = 0, rc = 0;
    u32 meta[3];
    bool cok[3], rok[3];
    #pragma unroll
    for (int k = 0; k < 3; k++) {
        const int a = t + k * BLOCK;               // unit-stride loads
        const u32 tok = (u32)tokmap[a];
        const bool lig = (s_lig[tok >> 6] >> (tok & 63)) & 1ULL;
        const u32 m0 = crd[a] != 0;
        const u32 m1 = crd[L + a] != 0;
        const bool any = (m0 | m1) != 0u;
        meta[k] = (u32)a | (tok << 12) | (m0 << 21) | (m1 << 22);
        cok[k] = (!lig) && any;
        rok[k] = lig && any;
        cc += cok[k] ? 1u : 0u;
        rc += rok[k] ? 1u : 0u;
    }

    u32 ci = cc, ri = rc;
    #pragma unroll
    for (int o = 1; o < 64; o <<= 1) {
        u32 cv = __shfl_up(ci, o, 64);
        u32 rv = __shfl_up(ri, o, 64);
        if (lane >= o) { ci += cv; ri += rv; }
    }
    if (lane == 63) { s_wtot[0][wv] = ci; s_wtot[1][wv] = ri; }
    __syncthreads();

    // Per-wave redundant scan of the 16 wave totals (no serial phase).
    u32 cex, rex;
    int ncol, nrow;
    {
        u32 cs = (lane < 16) ? s_wtot[0][lane] : 0u;
        u32 rs = (lane < 16) ? s_wtot[1][lane] : 0u;
        #pragma unroll
        for (int o = 1; o < 16; o <<= 1) {
            u32 cv = __shfl_up(cs, o, 64);
            u32 rv = __shfl_up(rs, o, 64);
            if (lane >= o && lane < 16) { cs += cv; rs += rv; }
        }
        cex = (wv == 0) ? 0u : __shfl(cs, wv - 1, 64);
        rex = (wv == 0) ? 0u : __shfl(rs, wv - 1, 64);
        ncol = (int)__shfl(cs, 15, 64);
        nrow = (int)__shfl(rs, 15, 64);
    }

    u32 coff = cex + (ci - cc);
    u32 roff = rex + (ri - rc);
    #pragma unroll
    for (int k = 0; k < 3; k++) {
        if (cok[k]) s_colmeta[coff++] = meta[k];
        if (rok[k]) s_rowlist[roff++] = meta[k];
    }
    __syncthreads();

    // ---------------- Phase B staging: bond masks + row coords ------------
    const int rpb = (nrow + GRID - 1) / GRID;
    const int r0 = blockIdx.x * rpb;
    const int r1 = (r0 + rpb < nrow) ? (r0 + rpb) : nrow;
    const int nr = (r1 > r0) ? (r1 - r0) : 0;

    // Bond rows: waves 0-7 take even rows, waves 8-15 odd rows.
    {
        const int half = wv >> 3;
        const int w8 = wv & 7;
        for (int r = half; r < nr; r += 2) {
            const u32 rm = s_rowlist[r0 + r];
            const u32 ta1 = (rm >> 12) & 0x1FF;
            const int tokidx = (w8 << 6) | lane;
            const bool bv = token_bonds[ta1 * NT + tokidx] != 0;
            const u64 bal = __ballot(bv);
            if (lane == 0) s_bond[r][w8] = bal;
        }
    }
    if (t < nr * 12) {
        const int r = t / 12, c = t % 12;
        const u32 rm = s_rowlist[r0 + r];
        const int a1 = (int)(rm & 0xFFF);
        const int batch = (c % 6) / 3;
        const int axis  = c % 3;
        const float* src = (c < 6) ? X : Xgt;
        s_rowc[r][c] = src[(batch * L + a1) * 3 + axis];
    }
    if (t < nr) s_rbits[t] = (s_rowlist[r0 + t] >> 21) & 3u;
    __syncthreads();

    // ---------------- Phase B: columns outer (regs), rows inner -----------
    double acc = 0.0;
    u32 cnt = 0;

    for (int j = t; j < ncol; j += BLOCK) {
        const u32 cm = s_colmeta[j];
        const int a2 = (int)(cm & 0xFFF);
        const u32 tok = (cm >> 12) & 0x1FF;
        const u32 cbits = (cm >> 21) & 3u;
        const u32 bhi = tok >> 6;
        const u64 bsel = 1ULL << (tok & 63);

        const int b0 = 3 * a2;
        const int b1 = 3 * L + 3 * a2;
        const float vx0 = X[b0 + 0], vy0 = X[b0 + 1], vz0 = X[b0 + 2];
        const float vx1 = X[b1 + 0], vy1 = X[b1 + 1], vz1 = X[b1 + 2];
        const float wx0 = Xgt[b0 + 0], wy0 = Xgt[b0 + 1], wz0 = Xgt[b0 + 2];
        const float wx1 = Xgt[b1 + 0], wy1 = Xgt[b1 + 1], wz1 = Xgt[b1 + 2];

        for (int r = 0; r < nr; r++) {
            const bool bond = (s_bond[r][bhi] & bsel) != 0ULL;
            const u32 mb = s_rbits[r] & cbits;

            const float p0x = s_rowc[r][0], p0y = s_rowc[r][1], p0z = s_rowc[r][2];
            const float p1x = s_rowc[r][3], p1y = s_rowc[r][4], p1z = s_rowc[r][5];
            const float g0x = s_rowc[r][6], g0y = s_rowc[r][7], g0z = s_rowc[r][8];
            const float g1x = s_rowc[r][9], g1y = s_rowc[r][10], g1z = s_rowc[r][11];

            // batch 0
            const float dgx0 = g0x - wx0, dgy0 = g0y - wy0, dgz0 = g0z - wz0;
            const float gt2_0 = dgx0 * dgx0 + dgy0 * dgy0 + dgz0 * dgz0;
            const float dpx0 = p0x - vx0, dpy0 = p0y - vy0, dpz0 = p0z - vz0;
            const float pr2_0 = dpx0 * dpx0 + dpy0 * dpy0 + dpz0 * dpz0;
            const float d0 = sqrtf(pr2_0) - sqrtf(gt2_0);
            const bool k0 = bond && (mb & 1u) && (gt2_0 < CUT2);
            // batch 1
            const float dgx1 = g1x - wx1, dgy1 = g1y - wy1, dgz1 = g1z - wz1;
            const float gt2_1 = dgx1 * dgx1 + dgy1 * dgy1 + dgz1 * dgz1;
            const float dpx1 = p1x - vx1, dpy1 = p1y - vy1, dpz1 = p1z - vz1;
            const float pr2_1 = dpx1 * dpx1 + dpy1 * dpy1 + dpz1 * dpz1;
            const float d1 = sqrtf(pr2_1) - sqrtf(gt2_1);
            const bool k1 = bond && (mb & 2u) && (gt2_1 < CUT2);

            const float e = (k0 ? d0 * d0 : 0.0f) + (k1 ? d1 * d1 : 0.0f);
            acc += (double)e;
            cnt += (k0 ? 1u : 0u) + (k1 ? 1u : 0u);
        }
    }

    // ---------------- Block reduction (16 waves) --------------------------
    #pragma unroll
    for (int o = 32; o > 0; o >>= 1) {
        acc += __shfl_down(acc, o, 64);
        cnt += __shfl_down(cnt, o, 64);
    }
    if (lane == 0) { s_rsum[wv] = acc; s_rcnt[wv] = cnt; }
    __syncthreads();
    if (t == 0) {
        double a = 0.0;
        u32 c = 0;
        #pragma unroll
        for (int i = 0; i < 16; i++) { a += s_rsum[i]; c += s_rcnt[i]; }
        part_sum[blockIdx.x] = a;
        part_cnt[blockIdx.x] = c;
    }
}

// ---------------------------------------------------------------------------
// Finalize: one block, deterministic reduction over GRID partials.
// ---------------------------------------------------------------------------
__global__ __launch_bounds__(256) void plbl_fin(
    const double* __restrict__ part_sum,
    const u32* __restrict__ part_cnt,
    float* __restrict__ out)
{
    const int t = threadIdx.x;
    const int lane = t & 63;
    const int wv = t >> 6;
    double a = part_sum[t];
    u32 c = part_cnt[t];
    #pragma unroll
    for (int o = 32; o > 0; o >>= 1) {
        a += __shfl_down(a, o, 64);
        c += __shfl_down(c, o, 64);
    }
    __shared__ double s_sum[4];
    __shared__ u32 s_cnt[4];
    if (lane == 0) { s_sum[wv] = a; s_cnt[wv] = c; }
    __syncthreads();
    if (t == 0) {
        const double sum = s_sum[0] + s_sum[1] + s_sum[2] + s_sum[3];
        const u32 cc = s_cnt[0] + s_cnt[1] + s_cnt[2] + s_cnt[3];
        const u32 n = cc ? cc : 1u;
        const float loss = (float)(sum / (double)n);
        out[0] = loss;
        out[1] = loss;
    }
}

extern "C" void kernel_launch(void* const* d_in, const int* in_sizes, int n_in,
                              void* d_out, int out_size, void* d_ws, size_t ws_size,
                              hipStream_t stream) {
    const int*   is_ligand   = (const int*)d_in[0];
    const int*   token_bonds = (const int*)d_in[1];
    const int*   tokmap      = (const int*)d_in[2];
    const int*   crd_mask    = (const int*)d_in[3];
    const float* X           = (const float*)d_in[4];
    const float* Xgt         = (const float*)d_in[5];
    float* out = (float*)d_out;

    char* w = (char*)d_ws;
    double* part_sum = (double*)(w + 0);
    u32*    part_cnt = (u32*)(w + 8 * GRID);

    plbl_main<<<GRID, BLOCK, 0, stream>>>(is_ligand, token_bonds, tokmap,
                                          crd_mask, X, Xgt,
                                          part_sum, part_cnt);
    plbl_fin<<<1, 256, 0, stream>>>(part_sum, part_cnt, out);
}